// Round 11
// baseline (624.548 us; speedup 1.0000x reference)
//
#include <hip/hip_runtime.h>
#include <math.h>

// Bahdanau attention, round 10: barrier-free K-loop, spill-free pipeline.
// R8 independence structure (no LDS, no barriers, per-lane A build, direct
// fragment-order B) but as a runtime loop of two ping-pong bodies: live
// ranges bounded -> no scratch spill (R8's 228MB WRITE_SIZE failure mode).
//   ws: dp | W2t (fragment order) | shared2 (eparts then pctx) = 2.625 MiB

#define BATCH 64
#define SEQ   4096
#define HID   512

typedef __attribute__((ext_vector_type(8))) short bf16x8;
typedef __attribute__((ext_vector_type(4))) float f32x4;

__device__ __forceinline__ float fast_tanh(float x) {
    return 1.0f - 2.0f / (__expf(2.0f * x) + 1.0f);
}

__device__ __forceinline__ unsigned cvt2(float lo, float hi) {
    unsigned r;
    asm("v_cvt_pk_bf16_f32 %0, %1, %2" : "=v"(r) : "v"(lo), "v"(hi));
    return r;
}

union bfpack { uint4 u; bf16x8 v; };

// ---------------------------------------------------------------------------
// K0: W2 fp32 -> bf16 in MFMA fragment order:
//   W2t[((gh*16 + kb)*4 + wv)*4 + n][lane][j]  (512 u16 per fragment)
// holds W2[g][k] with g = gh*256 + wv*64 + n*16 + (lane&15),
//                     k = kb*32 + (lane>>4)*8 + j.
// ---------------------------------------------------------------------------
__global__ void k_cvtW2(const float* __restrict__ W2, ushort* __restrict__ W2t)
{
    const int n  = blockIdx.x * 256 + threadIdx.x;   // 0..32767
    const int g  = n >> 6, kc = n & 63;
    const int kb = kc >> 2, rgl = kc & 3;
    const int gh = g >> 8, wv = (g >> 6) & 3, fn = (g >> 4) & 3, gl = g & 15;

    const float* src = W2 + (size_t)g * HID + kc * 8;
    const float4 x = *reinterpret_cast<const float4*>(src);
    const float4 y = *reinterpret_cast<const float4*>(src + 4);
    uint4 u;
    u.x = cvt2(x.x, x.y);  u.y = cvt2(x.z, x.w);
    u.z = cvt2(y.x, y.y);  u.w = cvt2(y.z, y.w);

    const size_t dst = (size_t)gh * 131072 + kb * 8192 + wv * 2048 + fn * 512
                     + (rgl * 16 + gl) * 8;
    *reinterpret_cast<uint4*>(W2t + dst) = u;
}

// ---------------------------------------------------------------------------
// K1: dp[b][g] = sum_h dh[b][h] * W1[g][h]  (fp32, tiny)
// ---------------------------------------------------------------------------
__global__ void k_decproj(const float* __restrict__ dh,
                          const float* __restrict__ W1,
                          float* __restrict__ dp)
{
    __shared__ float wrow[HID];
    const int g = blockIdx.x;
    const int t = threadIdx.x;
    for (int i = t; i < HID; i += 256) wrow[i] = W1[g * HID + i];
    __syncthreads();

    const int b = t >> 2, q = t & 3;
    const float* dhb = dh + b * HID + q * 128;
    const float* wr  = wrow + q * 128;
    float acc = 0.f;
    #pragma unroll 8
    for (int i = 0; i < 128; i += 4) {
        const float4 d4 = *reinterpret_cast<const float4*>(dhb + i);
        acc = fmaf(d4.x, wr[i + 0], acc);
        acc = fmaf(d4.y, wr[i + 1], acc);
        acc = fmaf(d4.z, wr[i + 2], acc);
        acc = fmaf(d4.w, wr[i + 3], acc);
    }
    acc += __shfl_xor(acc, 1);
    acc += __shfl_xor(acc, 2);
    if (q == 0) dp[b * HID + g] = acc;
}

// ---------------------------------------------------------------------------
// K2: energy partial GEMM, barrier-free + spill-free.
// grid = 8192 blocks, 256 thr (4 waves). Sibling g-halves 8 apart -> same XCD.
// Block tile 64s x 256g; wave wv owns g [gh*256+wv*64, +64), all 64 s.
// Runtime loop kb += 2 with two explicit bodies (all frag indices literal):
//   body: cvt t -> af (step kb); issue t = A(kb+1), bfr[other] = B(kb+1);
//         MFMA(af, bfr[this]).
// A-loads: 16 rows x 128 B per instr, line-exact. B: 16B/lane from L2.
// ---------------------------------------------------------------------------
#define ASTRIDE_M ((size_t)16 * BATCH * HID)

__global__ __launch_bounds__(256, 3)
void k_energy(const float* __restrict__ enc, const ushort* __restrict__ W2t,
              const float* __restrict__ dp,  const float* __restrict__ v,
              float* __restrict__ eparts)
{
    __shared__ float part[4][64];                      // 1 KiB (epilogue only)

    // block decode: idx -> (gh, schunk, b); siblings (gh=0/1) 8 apart.
    const int idx  = blockIdx.x;
    const int g16  = idx >> 4, rr = idx & 15;
    const int gh   = rr >> 3;
    const int pair = (g16 << 3) | (rr & 7);    // 0..4095
    const int schunk = pair & 63;
    const int b      = pair >> 6;
    const int s0     = schunk * 64;

    const int t    = threadIdx.x;
    const int lane = t & 63;
    const int wv   = t >> 6;                   // wave = N-block 0..3
    const int gl   = lane & 15, rg = lane >> 4;

    f32x4 acc[4][4];
    const f32x4 z = {0.f, 0.f, 0.f, 0.f};
    #pragma unroll
    for (int m = 0; m < 4; ++m)
        #pragma unroll
        for (int n = 0; n < 4; ++n) acc[m][n] = z;

    // A source: lane (gl,rg), frag m, step kb:
    //   enc[(s0 + m*16 + gl)][b][kb*32 + rg*8 .. +7]
    const float* a0 = enc + ((size_t)(s0 + gl) * BATCH + b) * HID + rg * 8;

    // B fragment base: step kb at +kb*8192, frag n at +n*512 (u16 units)
    const ushort* bptr = W2t + (size_t)gh * 131072 + wv * 2048 + lane * 8;

    bf16x8 af[4];          // current step's A fragments
    bf16x8 bfr[2][4];      // ping-pong B fragments
    float4 tf[8];          // in-flight fp32 A for next step

    // ---- prologue: issue t = A(0), bfr[0] = B(0) ----
    #pragma unroll
    for (int m = 0; m < 4; ++m) {
        const float* ap = a0 + m * ASTRIDE_M;
        tf[2 * m]     = *reinterpret_cast<const float4*>(ap);
        tf[2 * m + 1] = *reinterpret_cast<const float4*>(ap + 4);
    }
    #pragma unroll
    for (int n = 0; n < 4; ++n)
        bfr[0][n] = *reinterpret_cast<const bf16x8*>(bptr + n * 512);

    for (int kb = 0; kb < 16; kb += 2) {
        // ---- body 0: compute step kb ----
        {
            #pragma unroll
            for (int m = 0; m < 4; ++m) {
                bfpack w;
                w.u.x = cvt2(tf[2*m].x, tf[2*m].y);
                w.u.y = cvt2(tf[2*m].z, tf[2*m].w);
                w.u.z = cvt2(tf[2*m+1].x, tf[2*m+1].y);
                w.u.w = cvt2(tf[2*m+1].z, tf[2*m+1].w);
                af[m] = w.v;
            }
            // issue next-step inputs (A(kb+1), B(kb+1))
            {
                const float* ap1 = a0 + (kb + 1) * 32;
                #pragma unroll
                for (int m = 0; m < 4; ++m) {
                    const float* ap = ap1 + m * ASTRIDE_M;
                    tf[2 * m]     = *reinterpret_cast<const float4*>(ap);
                    tf[2 * m + 1] = *reinterpret_cast<const float4*>(ap + 4);
                }
                #pragma unroll
                for (int n = 0; n < 4; ++n)
                    bfr[1][n] = *reinterpret_cast<const bf16x8*>(
                        bptr + (size_t)(kb + 1) * 8192 + n * 512);
            }
            #pragma unroll
            for (int m = 0; m < 4; ++m)
                #pragma unroll
                for (int n = 0; n < 4; ++n)
                    acc[m][n] = __builtin_amdgcn_mfma_f32_16x16x32_bf16(
                        af[m], bfr[0][n], acc[m][n], 0, 0, 0);
        }
        // ---- body 1: compute step kb+1 ----
        {
            #pragma unroll
            for (int m = 0; m < 4; ++m) {
                bfpack w;
                w.u.x = cvt2(tf[2*m].x, tf[2*m].y);
                w.u.y = cvt2(tf[2*m].z, tf[2*m].w);
                w.u.z = cvt2(tf[2*m+1].x, tf[2*m+1].y);
                w.u.w = cvt2(tf[2*m+1].z, tf[2*m+1].w);
                af[m] = w.v;
            }
            if (kb < 14) {   // issue A(kb+2), B(kb+2); guard: kb=14 -> step 16 OOB
                const float* ap2 = a0 + (kb + 2) * 32;
                #pragma unroll
                for (int m = 0; m < 4; ++m) {
                    const float* ap = ap2 + m * ASTRIDE_M;
                    tf[2 * m]     = *reinterpret_cast<const float4*>(ap);
                    tf[2 * m + 1] = *reinterpret_cast<const float4*>(ap + 4);
                }
                #pragma unroll
                for (int n = 0; n < 4; ++n)
                    bfr[0][n] = *reinterpret_cast<const bf16x8*>(
                        bptr + (size_t)(kb + 2) * 8192 + n * 512);
            }
            #pragma unroll
            for (int m = 0; m < 4; ++m)
                #pragma unroll
                for (int n = 0; n < 4; ++n)
                    acc[m][n] = __builtin_amdgcn_mfma_f32_16x16x32_bf16(
                        af[m], bfr[1][n], acc[m][n], 0, 0, 0);
        }
    }

    // epilogue: partial energy over this block's 256 g
    float dpv[4], vv[4];
    #pragma unroll
    for (int n = 0; n < 4; ++n) {
        const int g = gh * 256 + wv * 64 + n * 16 + gl;
        dpv[n] = dp[b * HID + g];
        vv[n]  = v[g];
    }
    float p[4][4];
    #pragma unroll
    for (int m = 0; m < 4; ++m)
        #pragma unroll
        for (int r = 0; r < 4; ++r) p[m][r] = 0.f;
    #pragma unroll
    for (int n = 0; n < 4; ++n)
        #pragma unroll
        for (int m = 0; m < 4; ++m)
            #pragma unroll
            for (int r = 0; r < 4; ++r)
                p[m][r] += fast_tanh(dpv[n] + acc[m][n][r]) * vv[n];

    #pragma unroll
    for (int m = 0; m < 4; ++m)
        #pragma unroll
        for (int r = 0; r < 4; ++r) {
            float x = p[m][r];
            x += __shfl_xor(x, 1);
            x += __shfl_xor(x, 2);
            x += __shfl_xor(x, 4);
            x += __shfl_xor(x, 8);
            p[m][r] = x;
        }
    if (gl == 0) {
        #pragma unroll
        for (int m = 0; m < 4; ++m)
            #pragma unroll
            for (int r = 0; r < 4; ++r)
                part[wv][m * 16 + rg * 4 + r] = p[m][r];
    }
    __syncthreads();

    if (t < 64) {
        const float e = part[0][t] + part[1][t] + part[2][t] + part[3][t];
        eparts[(size_t)gh * BATCH * SEQ + (size_t)b * SEQ + s0 + t] = e;
    }
}

// ---------------------------------------------------------------------------
// K3: softmax over s per b; sums the two g-half partials, writes attn.
// ---------------------------------------------------------------------------
__global__ void k_softmax(const float* __restrict__ eparts,
                          float* __restrict__ attn)
{
    __shared__ float redm[4], reds[4];
    const int b = blockIdx.x, t = threadIdx.x;
    const float* e0 = eparts + (size_t)b * SEQ;
    const float* e1 = eparts + (size_t)BATCH * SEQ + (size_t)b * SEQ;

    float4 ev[4];
    float m = -3.4e38f;
    #pragma unroll
    for (int i = 0; i < 4; ++i) {
        const float4 x = *reinterpret_cast<const float4*>(e0 + i * 1024 + t * 4);
        const float4 y = *reinterpret_cast<const float4*>(e1 + i * 1024 + t * 4);
        ev[i] = make_float4(x.x + y.x, x.y + y.y, x.z + y.z, x.w + y.w);
        m = fmaxf(m, fmaxf(fmaxf(ev[i].x, ev[i].y), fmaxf(ev[i].z, ev[i].w)));
    }
    #pragma unroll
    for (int off = 1; off < 64; off <<= 1) m = fmaxf(m, __shfl_xor(m, off));
    if ((t & 63) == 0) redm[t >> 6] = m;
    __syncthreads();
    m = fmaxf(fmaxf(redm[0], redm[1]), fmaxf(redm[2], redm[3]));

    float s = 0.f;
    #pragma unroll
    for (int i = 0; i < 4; ++i) {
        ev[i].x = __expf(ev[i].x - m);  ev[i].y = __expf(ev[i].y - m);
        ev[i].z = __expf(ev[i].z - m);  ev[i].w = __expf(ev[i].w - m);
        s += (ev[i].x + ev[i].y) + (ev[i].z + ev[i].w);
    }
    #pragma unroll
    for (int off = 1; off < 64; off <<= 1) s += __shfl_xor(s, off);
    if ((t & 63) == 0) reds[t >> 6] = s;
    __syncthreads();
    s = (reds[0] + reds[1]) + (reds[2] + reds[3]);
    const float inv = 1.0f / s;

    float* o = attn + (size_t)b * SEQ;
    #pragma unroll
    for (int i = 0; i < 4; ++i) {
        const float4 w4 = make_float4(ev[i].x * inv, ev[i].y * inv,
                                      ev[i].z * inv, ev[i].w * inv);
        *reinterpret_cast<float4*>(o + i * 1024 + t * 4) = w4;
    }
}

// ---------------------------------------------------------------------------
// K4: partial context. grid = (64 b, 16 s-splits), 256 threads.
// ---------------------------------------------------------------------------
__global__ void k_ctxpart(const float* __restrict__ enc,
                          const float* __restrict__ attn,
                          float* __restrict__ pctx)
{
    __shared__ float w[256];
    const int b  = blockIdx.x;
    const int sp = blockIdx.y;
    const int t  = threadIdx.x;

    w[t] = attn[(size_t)b * SEQ + sp * 256 + t];
    __syncthreads();

    const float2* e2 = reinterpret_cast<const float2*>(enc);
    size_t idx = ((size_t)sp * 256 * BATCH + b) * (HID / 2) + t;
    const size_t stride = (size_t)BATCH * (HID / 2);

    float ax = 0.f, ay = 0.f;
    #pragma unroll 4
    for (int s = 0; s < 256; ++s) {
        const float2 ev = e2[idx];
        const float ws = w[s];
        ax = fmaf(ws, ev.x, ax);
        ay = fmaf(ws, ev.y, ay);
        idx += stride;
    }
    float2* p2 = reinterpret_cast<float2*>(pctx);
    p2[((size_t)sp * BATCH + b) * (HID / 2) + t] = make_float2(ax, ay);
}

// ---------------------------------------------------------------------------
// K5: context[b][h] = sum over 16 splits.
// ---------------------------------------------------------------------------
__global__ void k_ctxsum(const float* __restrict__ pctx,
                         float* __restrict__ ctx)
{
    const int i = blockIdx.x * 256 + threadIdx.x;
    float s = 0.f;
    #pragma unroll
    for (int sp = 0; sp < 16; ++sp) s += pctx[(size_t)sp * BATCH * HID + i];
    ctx[i] = s;
}

// ---------------------------------------------------------------------------
extern "C" void kernel_launch(void* const* d_in, const int* in_sizes, int n_in,
                              void* d_out, int out_size, void* d_ws, size_t ws_size,
                              hipStream_t stream)
{
    const float* dh  = (const float*)d_in[0];
    const float* enc = (const float*)d_in[1];
    const float* W1  = (const float*)d_in[2];
    const float* W2  = (const float*)d_in[3];
    const float* v   = (const float*)d_in[4];

    float* out  = (float*)d_out;
    float* ctx  = out;                           // 64*512
    float* attn = out + BATCH * HID;             // 64*4096

    float*  dp      = (float*)d_ws;                  // 128 KiB
    ushort* W2t     = (ushort*)(dp + BATCH * HID);   // 512 KiB (fragment order)
    float*  shared2 = (float*)(W2t + HID * HID);     // 2 MiB, dual-use:
    float*  eparts  = shared2;                       //   [2][B][S] until softmax
    float*  pctx    = shared2;                       //   [16][B][H] after

    k_cvtW2  <<<128, 256, 0, stream>>>(W2, W2t);
    k_decproj<<<HID, 256, 0, stream>>>(dh, W1, dp);
    k_energy <<<8192, 256, 0, stream>>>(enc, W2t, dp, v, eparts);
    k_softmax<<<BATCH, 256, 0, stream>>>(eparts, attn);
    k_ctxpart<<<dim3(BATCH, 16), 256, 0, stream>>>(enc, attn, pctx);
    k_ctxsum <<<BATCH * HID / 256, 256, 0, stream>>>(pctx, ctx);
}

// Round 12
// 321.403 us; speedup vs baseline: 1.9432x; 1.9432x over previous
//
#include <hip/hip_runtime.h>
#include <math.h>

// Bahdanau attention, round 11: single-barrier triple-buffered energy K-loop.
// Lessons: barrier-free (R8/R10) = 2x WORSE (A-latency chain + duplicated
// loads); LDS staging is load-bearing. This keeps R7's staging but cuts the
// sync cost: ONE raw s_barrier per step (no vmcnt drain), As triple-buffered
// (write kb+1 pre-barrier, read kb post-barrier -- safe because each wave's
// reads are lgkm-complete before it passes the NEXT barrier), bfr issued at
// step top (compiler vmcnt(2) leaves A-prefetch flying), A 1-step reg flight.
//   ws: dp | W2t (fragment order) | shared2 (eparts then pctx) = 2.625 MiB

#define BATCH 64
#define SEQ   4096
#define HID   512

typedef __attribute__((ext_vector_type(8))) short bf16x8;
typedef __attribute__((ext_vector_type(4))) float f32x4;

__device__ __forceinline__ float fast_tanh(float x) {
    return 1.0f - 2.0f / (__expf(2.0f * x) + 1.0f);
}

__device__ __forceinline__ unsigned cvt2(float lo, float hi) {
    unsigned r;
    asm("v_cvt_pk_bf16_f32 %0, %1, %2" : "=v"(r) : "v"(lo), "v"(hi));
    return r;
}

// ---------------------------------------------------------------------------
// K0: W2 fp32 -> bf16 in MFMA fragment order:
//   W2t[((gh*16 + kb)*4 + wv)*4 + n][lane][j]  (512 u16 per fragment)
// holds W2[g][k] with g = gh*256 + wv*64 + n*16 + (lane&15),
//                     k = kb*32 + (lane>>4)*8 + j.
// ---------------------------------------------------------------------------
__global__ void k_cvtW2(const float* __restrict__ W2, ushort* __restrict__ W2t)
{
    const int n  = blockIdx.x * 256 + threadIdx.x;   // 0..32767
    const int g  = n >> 6, kc = n & 63;
    const int kb = kc >> 2, rgl = kc & 3;
    const int gh = g >> 8, wv = (g >> 6) & 3, fn = (g >> 4) & 3, gl = g & 15;

    const float* src = W2 + (size_t)g * HID + kc * 8;
    const float4 x = *reinterpret_cast<const float4*>(src);
    const float4 y = *reinterpret_cast<const float4*>(src + 4);
    uint4 u;
    u.x = cvt2(x.x, x.y);  u.y = cvt2(x.z, x.w);
    u.z = cvt2(y.x, y.y);  u.w = cvt2(y.z, y.w);

    const size_t dst = (size_t)gh * 131072 + kb * 8192 + wv * 2048 + fn * 512
                     + (rgl * 16 + gl) * 8;
    *reinterpret_cast<uint4*>(W2t + dst) = u;
}

// ---------------------------------------------------------------------------
// K1: dp[b][g] = sum_h dh[b][h] * W1[g][h]  (fp32, tiny)
// ---------------------------------------------------------------------------
__global__ void k_decproj(const float* __restrict__ dh,
                          const float* __restrict__ W1,
                          float* __restrict__ dp)
{
    __shared__ float wrow[HID];
    const int g = blockIdx.x;
    const int t = threadIdx.x;
    for (int i = t; i < HID; i += 256) wrow[i] = W1[g * HID + i];
    __syncthreads();

    const int b = t >> 2, q = t & 3;
    const float* dhb = dh + b * HID + q * 128;
    const float* wr  = wrow + q * 128;
    float acc = 0.f;
    #pragma unroll 8
    for (int i = 0; i < 128; i += 4) {
        const float4 d4 = *reinterpret_cast<const float4*>(dhb + i);
        acc = fmaf(d4.x, wr[i + 0], acc);
        acc = fmaf(d4.y, wr[i + 1], acc);
        acc = fmaf(d4.z, wr[i + 2], acc);
        acc = fmaf(d4.w, wr[i + 3], acc);
    }
    acc += __shfl_xor(acc, 1);
    acc += __shfl_xor(acc, 2);
    if (q == 0) dp[b * HID + g] = acc;
}

// ---------------------------------------------------------------------------
// K2: energy partial GEMM. grid = 8192 blocks, 256 thr (4 waves).
// Sibling g-halves of one (s-chunk, b) at blockIdx distance 8 -> same XCD.
// Block tile 64s x 256g, BK=32, 16 K-steps fully unrolled.
// Step kb: issue bfr(kb); issue A(kb+2)->ar[kb&1]; cvt ar[(kb+1)&1] ->
//          ds_write As[(kb+1)%3]; lgkm(0); s_barrier (raw, VMEM stays in
//          flight); ds_read af from As[kb%3]; 16 MFMA.
// Triple-buffer safety: a wave's reads of As[kb%3] are lgkm-complete before
// it passes barrier kb+1; the next write to that buffer happens at step kb+2,
// after barrier kb+1 -> no cross-wave race with only one barrier per step.
// ---------------------------------------------------------------------------
#define LDA 40

__global__ __launch_bounds__(256, 4)
void k_energy(const float* __restrict__ enc, const ushort* __restrict__ W2t,
              const float* __restrict__ dp,  const float* __restrict__ v,
              float* __restrict__ eparts)
{
    __shared__ __align__(16) ushort As[3][64 * LDA];   // 3 x 5 KiB
    __shared__ float part[4][64];                      // 1 KiB

    // block decode: idx -> (gh, schunk, b); siblings (gh=0/1) 8 apart.
    const int idx  = blockIdx.x;
    const int g16  = idx >> 4, rr = idx & 15;
    const int gh   = rr >> 3;
    const int pair = (g16 << 3) | (rr & 7);    // 0..4095
    const int schunk = pair & 63;
    const int b      = pair >> 6;
    const int s0     = schunk * 64;

    const int t    = threadIdx.x;
    const int lane = t & 63;
    const int wv   = t >> 6;                   // wave = N-block 0..3
    const int gl   = lane & 15, rg = lane >> 4;

    f32x4 acc[4][4];
    const f32x4 z = {0.f, 0.f, 0.f, 0.f};
    #pragma unroll
    for (int m = 0; m < 4; ++m)
        #pragma unroll
        for (int n = 0; n < 4; ++n) acc[m][n] = z;

    // A staging: thread -> (row = t>>2 in [0,64), kq = t&3), 8 floats/step
    const int arow = t >> 2, akq = t & 3;
    const float* aptr = enc + ((size_t)(s0 + arow) * BATCH + b) * HID + akq * 8;
    const int awoff = arow * LDA + akq * 8;    // u16 offset within a buffer
    const int aroff = gl * LDA + rg * 8;       // fragment read base (m at +m*640)

    // B fragment base: step kb at +kb*8192, frag n at +n*512 (u16 units)
    const ushort* bptr = W2t + (size_t)gh * 131072 + wv * 2048 + lane * 8;

    float4 ar[2][2];       // ping-pong in-flight fp32 A rows
    bf16x8 bfr[4];         // current step's B fragments

    // ---- prologue: stage A(0) -> As[0]; issue A(1) -> ar[1] ----
    {
        const float4 p0 = *reinterpret_cast<const float4*>(aptr);
        const float4 p1 = *reinterpret_cast<const float4*>(aptr + 4);
        uint4 aw;
        aw.x = cvt2(p0.x, p0.y);  aw.y = cvt2(p0.z, p0.w);
        aw.z = cvt2(p1.x, p1.y);  aw.w = cvt2(p1.z, p1.w);
        *reinterpret_cast<uint4*>(&As[0][awoff]) = aw;
    }
    ar[1][0] = *reinterpret_cast<const float4*>(aptr + 32);
    ar[1][1] = *reinterpret_cast<const float4*>(aptr + 36);
    asm volatile("s_waitcnt lgkmcnt(0)" ::: "memory");
    __builtin_amdgcn_sched_barrier(0);
    __builtin_amdgcn_s_barrier();              // As[0] visible

    // ---- main loop (fully unrolled; kb%3, kb&1 all literal) ----
    #pragma unroll
    for (int kb = 0; kb < 16; ++kb) {
        const int c3 = kb % 3, n3 = (kb + 1) % 3;

        // 1. B fragments for THIS step (consumed ~300 cyc later at MFMA)
        #pragma unroll
        for (int n = 0; n < 4; ++n)
            bfr[n] = *reinterpret_cast<const bf16x8*>(
                bptr + (size_t)kb * 8192 + n * 512);

        // 2. issue A(kb+2) -> ar[kb&1] (1-step flight; consumed at kb+1)
        if (kb <= 13) {
            ar[kb & 1][0] = *reinterpret_cast<const float4*>(aptr + (kb + 2) * 32);
            ar[kb & 1][1] = *reinterpret_cast<const float4*>(aptr + (kb + 2) * 32 + 4);
        }

        // 3. stage A(kb+1) from ar[(kb+1)&1] -> As[n3] (pre-barrier)
        if (kb <= 14) {
            const float4 p0 = ar[(kb + 1) & 1][0], p1 = ar[(kb + 1) & 1][1];
            uint4 aw;
            aw.x = cvt2(p0.x, p0.y);  aw.y = cvt2(p0.z, p0.w);
            aw.z = cvt2(p1.x, p1.y);  aw.w = cvt2(p1.z, p1.w);
            *reinterpret_cast<uint4*>(&As[n3][awoff]) = aw;
        }

        // 4. single raw barrier: LDS drained, VMEM (A(kb+2), bfr) keeps flying
        asm volatile("s_waitcnt lgkmcnt(0)" ::: "memory");
        __builtin_amdgcn_sched_barrier(0);
        __builtin_amdgcn_s_barrier();

        // 5. compute step kb from As[c3]
        #pragma unroll
        for (int m = 0; m < 4; ++m) {
            const bf16x8 af = *reinterpret_cast<const bf16x8*>(
                &As[c3][aroff + m * 16 * LDA]);
            #pragma unroll
            for (int n = 0; n < 4; ++n)
                acc[m][n] = __builtin_amdgcn_mfma_f32_16x16x32_bf16(
                    af, bfr[n], acc[m][n], 0, 0, 0);
        }
    }

    // epilogue: partial energy over this block's 256 g
    float dpv[4], vv[4];
    #pragma unroll
    for (int n = 0; n < 4; ++n) {
        const int g = gh * 256 + wv * 64 + n * 16 + gl;
        dpv[n] = dp[b * HID + g];
        vv[n]  = v[g];
    }
    float p[4][4];
    #pragma unroll
    for (int m = 0; m < 4; ++m)
        #pragma unroll
        for (int r = 0; r < 4; ++r) p[m][r] = 0.f;
    #pragma unroll
    for (int n = 0; n < 4; ++n)
        #pragma unroll
        for (int m = 0; m < 4; ++m)
            #pragma unroll
            for (int r = 0; r < 4; ++r)
                p[m][r] += fast_tanh(dpv[n] + acc[m][n][r]) * vv[n];

    #pragma unroll
    for (int m = 0; m < 4; ++m)
        #pragma unroll
        for (int r = 0; r < 4; ++r) {
            float x = p[m][r];
            x += __shfl_xor(x, 1);
            x += __shfl_xor(x, 2);
            x += __shfl_xor(x, 4);
            x += __shfl_xor(x, 8);
            p[m][r] = x;
        }
    if (gl == 0) {
        #pragma unroll
        for (int m = 0; m < 4; ++m)
            #pragma unroll
            for (int r = 0; r < 4; ++r)
                part[wv][m * 16 + rg * 4 + r] = p[m][r];
    }
    __syncthreads();

    if (t < 64) {
        const float e = part[0][t] + part[1][t] + part[2][t] + part[3][t];
        eparts[(size_t)gh * BATCH * SEQ + (size_t)b * SEQ + s0 + t] = e;
    }
}

// ---------------------------------------------------------------------------
// K3: softmax over s per b; sums the two g-half partials, writes attn.
// ---------------------------------------------------------------------------
__global__ void k_softmax(const float* __restrict__ eparts,
                          float* __restrict__ attn)
{
    __shared__ float redm[4], reds[4];
    const int b = blockIdx.x, t = threadIdx.x;
    const float* e0 = eparts + (size_t)b * SEQ;
    const float* e1 = eparts + (size_t)BATCH * SEQ + (size_t)b * SEQ;

    float4 ev[4];
    float m = -3.4e38f;
    #pragma unroll
    for (int i = 0; i < 4; ++i) {
        const float4 x = *reinterpret_cast<const float4*>(e0 + i * 1024 + t * 4);
        const float4 y = *reinterpret_cast<const float4*>(e1 + i * 1024 + t * 4);
        ev[i] = make_float4(x.x + y.x, x.y + y.y, x.z + y.z, x.w + y.w);
        m = fmaxf(m, fmaxf(fmaxf(ev[i].x, ev[i].y), fmaxf(ev[i].z, ev[i].w)));
    }
    #pragma unroll
    for (int off = 1; off < 64; off <<= 1) m = fmaxf(m, __shfl_xor(m, off));
    if ((t & 63) == 0) redm[t >> 6] = m;
    __syncthreads();
    m = fmaxf(fmaxf(redm[0], redm[1]), fmaxf(redm[2], redm[3]));

    float s = 0.f;
    #pragma unroll
    for (int i = 0; i < 4; ++i) {
        ev[i].x = __expf(ev[i].x - m);  ev[i].y = __expf(ev[i].y - m);
        ev[i].z = __expf(ev[i].z - m);  ev[i].w = __expf(ev[i].w - m);
        s += (ev[i].x + ev[i].y) + (ev[i].z + ev[i].w);
    }
    #pragma unroll
    for (int off = 1; off < 64; off <<= 1) s += __shfl_xor(s, off);
    if ((t & 63) == 0) reds[t >> 6] = s;
    __syncthreads();
    s = (reds[0] + reds[1]) + (reds[2] + reds[3]);
    const float inv = 1.0f / s;

    float* o = attn + (size_t)b * SEQ;
    #pragma unroll
    for (int i = 0; i < 4; ++i) {
        const float4 w4 = make_float4(ev[i].x * inv, ev[i].y * inv,
                                      ev[i].z * inv, ev[i].w * inv);
        *reinterpret_cast<float4*>(o + i * 1024 + t * 4) = w4;
    }
}

// ---------------------------------------------------------------------------
// K4: partial context. grid = (64 b, 16 s-splits), 256 threads.
// ---------------------------------------------------------------------------
__global__ void k_ctxpart(const float* __restrict__ enc,
                          const float* __restrict__ attn,
                          float* __restrict__ pctx)
{
    __shared__ float w[256];
    const int b  = blockIdx.x;
    const int sp = blockIdx.y;
    const int t  = threadIdx.x;

    w[t] = attn[(size_t)b * SEQ + sp * 256 + t];
    __syncthreads();

    const float2* e2 = reinterpret_cast<const float2*>(enc);
    size_t idx = ((size_t)sp * 256 * BATCH + b) * (HID / 2) + t;
    const size_t stride = (size_t)BATCH * (HID / 2);

    float ax = 0.f, ay = 0.f;
    #pragma unroll 4
    for (int s = 0; s < 256; ++s) {
        const float2 ev = e2[idx];
        const float ws = w[s];
        ax = fmaf(ws, ev.x, ax);
        ay = fmaf(ws, ev.y, ay);
        idx += stride;
    }
    float2* p2 = reinterpret_cast<float2*>(pctx);
    p2[((size_t)sp * BATCH + b) * (HID / 2) + t] = make_float2(ax, ay);
}

// ---------------------------------------------------------------------------
// K5: context[b][h] = sum over 16 splits.
// ---------------------------------------------------------------------------
__global__ void k_ctxsum(const float* __restrict__ pctx,
                         float* __restrict__ ctx)
{
    const int i = blockIdx.x * 256 + threadIdx.x;
    float s = 0.f;
    #pragma unroll
    for (int sp = 0; sp < 16; ++sp) s += pctx[(size_t)sp * BATCH * HID + i];
    ctx[i] = s;
}

// ---------------------------------------------------------------------------
extern "C" void kernel_launch(void* const* d_in, const int* in_sizes, int n_in,
                              void* d_out, int out_size, void* d_ws, size_t ws_size,
                              hipStream_t stream)
{
    const float* dh  = (const float*)d_in[0];
    const float* enc = (const float*)d_in[1];
    const float* W1  = (const float*)d_in[2];
    const float* W2  = (const float*)d_in[3];
    const float* v   = (const float*)d_in[4];

    float* out  = (float*)d_out;
    float* ctx  = out;                           // 64*512
    float* attn = out + BATCH * HID;             // 64*4096

    float*  dp      = (float*)d_ws;                  // 128 KiB
    ushort* W2t     = (ushort*)(dp + BATCH * HID);   // 512 KiB (fragment order)
    float*  shared2 = (float*)(W2t + HID * HID);     // 2 MiB, dual-use:
    float*  eparts  = shared2;                       //   [2][B][S] until softmax
    float*  pctx    = shared2;                       //   [16][B][H] after

    k_cvtW2  <<<128, 256, 0, stream>>>(W2, W2t);
    k_decproj<<<HID, 256, 0, stream>>>(dh, W1, dp);
    k_energy <<<8192, 256, 0, stream>>>(enc, W2t, dp, v, eparts);
    k_softmax<<<BATCH, 256, 0, stream>>>(eparts, attn);
    k_ctxpart<<<dim3(BATCH, 16), 256, 0, stream>>>(enc, attn, pctx);
    k_ctxsum <<<BATCH * HID / 256, 256, 0, stream>>>(pctx, ctx);
}

// Round 13
// 318.012 us; speedup vs baseline: 1.9639x; 1.0107x over previous
//
#include <hip/hip_runtime.h>
#include <math.h>

// Bahdanau attention, round 12: phase-split energy kernel.
// Phase 1: block converts its 64x512 enc slice fp32->bf16 into a swizzled
//          64KiB LDS tile (one __syncthreads).
// Phase 2: barrier-free K-loop -- af from immutable LDS, bfr from
//          fragment-ordered W2t via uniform base + 32-bit voffset. No cvt,
//          no ds_write, no barriers on the critical path.
// Block = 64s x 512g (8 waves, wave tile 64x64), grid 4096. No gh split ->
// enc converted once (halves cvt VALU). Energy -> d_out attn region,
// softmax in place.
//   ws: dp | W2t (fragment order) | pctx = 2.625 MiB

#define BATCH 64
#define SEQ   4096
#define HID   512

typedef __attribute__((ext_vector_type(8))) short bf16x8;
typedef __attribute__((ext_vector_type(4))) float f32x4;

__device__ __forceinline__ float fast_tanh(float x) {
    return 1.0f - 2.0f / (__expf(2.0f * x) + 1.0f);
}

__device__ __forceinline__ unsigned cvt2(float lo, float hi) {
    unsigned r;
    asm("v_cvt_pk_bf16_f32 %0, %1, %2" : "=v"(r) : "v"(lo), "v"(hi));
    return r;
}

// ---------------------------------------------------------------------------
// K0: W2 fp32 -> bf16 in MFMA fragment order (no gh split):
//   u16 index = kb*16384 + wn*2048 + fn*512 + ((k>>3)&3)*128 + (g&15)*8
// holds W2[g][k], g = wn*64 + fn*16 + (g&15), k = kb*32 + rgl*8 + j.
// ---------------------------------------------------------------------------
__global__ void k_cvtW2(const float* __restrict__ W2, ushort* __restrict__ W2t)
{
    const int n  = blockIdx.x * 256 + threadIdx.x;   // 0..32767
    const int g  = n >> 6, kc = n & 63;
    const int kb = kc >> 2, rgl = kc & 3;
    const int wn = g >> 6, fn = (g >> 4) & 3, gl = g & 15;

    const float* src = W2 + (size_t)g * HID + kc * 8;
    const float4 x = *reinterpret_cast<const float4*>(src);
    const float4 y = *reinterpret_cast<const float4*>(src + 4);
    uint4 u;
    u.x = cvt2(x.x, x.y);  u.y = cvt2(x.z, x.w);
    u.z = cvt2(y.x, y.y);  u.w = cvt2(y.z, y.w);

    const size_t dst = (size_t)kb * 16384 + wn * 2048 + fn * 512
                     + (rgl * 16 + gl) * 8;
    *reinterpret_cast<uint4*>(W2t + dst) = u;
}

// ---------------------------------------------------------------------------
// K1: dp[b][g] = sum_h dh[b][h] * W1[g][h]  (fp32, tiny)
// ---------------------------------------------------------------------------
__global__ void k_decproj(const float* __restrict__ dh,
                          const float* __restrict__ W1,
                          float* __restrict__ dp)
{
    __shared__ float wrow[HID];
    const int g = blockIdx.x;
    const int t = threadIdx.x;
    for (int i = t; i < HID; i += 256) wrow[i] = W1[g * HID + i];
    __syncthreads();

    const int b = t >> 2, q = t & 3;
    const float* dhb = dh + b * HID + q * 128;
    const float* wr  = wrow + q * 128;
    float acc = 0.f;
    #pragma unroll 8
    for (int i = 0; i < 128; i += 4) {
        const float4 d4 = *reinterpret_cast<const float4*>(dhb + i);
        acc = fmaf(d4.x, wr[i + 0], acc);
        acc = fmaf(d4.y, wr[i + 1], acc);
        acc = fmaf(d4.z, wr[i + 2], acc);
        acc = fmaf(d4.w, wr[i + 3], acc);
    }
    acc += __shfl_xor(acc, 1);
    acc += __shfl_xor(acc, 2);
    if (q == 0) dp[b * HID + g] = acc;
}

// ---------------------------------------------------------------------------
// K2: energy GEMM, phase-split. grid = 4096 blocks (schunk = idx&63,
// b = idx>>6), 512 thr (8 waves). Wave w owns g [w*64, w*64+64).
//
// Phase 1 (conversion): round r in 0..7 -> wave w converts enc row r*8+w
//   (wait, row = r*8 + w covers 64 rows over 8 rounds x 8 waves):
//   lane l loads 32B (2 float4) of the 2KB row, cvt_pk -> 16B, ds_write_b128
//   at As[row*1024 + (l ^ (row&7))*16]  (XOR swizzle, conflict-free).
//
// Phase 2 (K-loop, NO barriers): step kb in 0..15:
//   af[m] = ds_read_b128 at gl*1024 + ((4kb+rg)^(gl&7))*16 + m*16384
//   bfr[n] = global 16B at W2t + kb*32768 (uniform) + w*4096 + lane*16
//            + n*1024 (imm)
//   16 MFMA. LDS tile immutable -> compiler pipelines freely across steps.
// ---------------------------------------------------------------------------
__global__ __launch_bounds__(512, 2)
void k_energy(const float* __restrict__ enc, const ushort* __restrict__ W2t,
              const float* __restrict__ dp,  const float* __restrict__ v,
              float* __restrict__ energy)
{
    __shared__ __align__(16) ushort As[64 * 512];      // 64 KiB (swizzled)
    __shared__ float part[8][64];                      //  2 KiB

    const int idx    = blockIdx.x;
    const int schunk = idx & 63;
    const int b      = idx >> 6;
    const int s0     = schunk * 64;

    const int t    = threadIdx.x;
    const int lane = t & 63;
    const int w    = t >> 6;                   // wave 0..7 -> g block
    const int gl   = lane & 15, rg = lane >> 4;

    // ---- phase 1: convert enc slice into LDS ----
    #pragma unroll
    for (int r = 0; r < 8; ++r) {
        const int row = r * 8 + w;
        const float* rp = enc + ((size_t)(s0 + row) * BATCH + b) * HID + lane * 8;
        const float4 x = *reinterpret_cast<const float4*>(rp);
        const float4 y = *reinterpret_cast<const float4*>(rp + 4);
        uint4 u;
        u.x = cvt2(x.x, x.y);  u.y = cvt2(x.z, x.w);
        u.z = cvt2(y.x, y.y);  u.w = cvt2(y.z, y.w);
        const int slot = lane ^ (row & 7);
        *reinterpret_cast<uint4*>(
            reinterpret_cast<char*>(As) + row * 1024 + slot * 16) = u;
    }
    __syncthreads();

    // ---- phase 2: barrier-free K-loop ----
    f32x4 acc[4][4];
    const f32x4 z = {0.f, 0.f, 0.f, 0.f};
    #pragma unroll
    for (int m = 0; m < 4; ++m)
        #pragma unroll
        for (int n = 0; n < 4; ++n) acc[m][n] = z;

    const char* asbase = reinterpret_cast<const char*>(As) + gl * 1024;
    const char* bbase  = reinterpret_cast<const char*>(W2t)
                       + w * 4096 + lane * 16;
    const int   gmask  = gl & 7;

    #pragma unroll
    for (int kb = 0; kb < 16; ++kb) {
        bf16x8 bfr[4];
        const char* bstep = bbase + kb * 32768;   // uniform part -> SGPR
        #pragma unroll
        for (int n = 0; n < 4; ++n)
            bfr[n] = *reinterpret_cast<const bf16x8*>(bstep + n * 1024);

        const char* arow = asbase + ((4 * kb + rg) ^ gmask) * 16;
        #pragma unroll
        for (int m = 0; m < 4; ++m) {
            const bf16x8 af = *reinterpret_cast<const bf16x8*>(arow + m * 16384);
            #pragma unroll
            for (int n = 0; n < 4; ++n)
                acc[m][n] = __builtin_amdgcn_mfma_f32_16x16x32_bf16(
                    af, bfr[n], acc[m][n], 0, 0, 0);
        }
    }

    // ---- epilogue: energy over this block's full 512 g ----
    float dpv[4], vv[4];
    #pragma unroll
    for (int n = 0; n < 4; ++n) {
        const int g = w * 64 + n * 16 + gl;
        dpv[n] = dp[b * HID + g];
        vv[n]  = v[g];
    }
    float p[4][4];
    #pragma unroll
    for (int m = 0; m < 4; ++m)
        #pragma unroll
        for (int r = 0; r < 4; ++r) p[m][r] = 0.f;
    #pragma unroll
    for (int n = 0; n < 4; ++n)
        #pragma unroll
        for (int m = 0; m < 4; ++m)
            #pragma unroll
            for (int r = 0; r < 4; ++r)
                p[m][r] += fast_tanh(dpv[n] + acc[m][n][r]) * vv[n];

    #pragma unroll
    for (int m = 0; m < 4; ++m)
        #pragma unroll
        for (int r = 0; r < 4; ++r) {
            float x = p[m][r];
            x += __shfl_xor(x, 1);
            x += __shfl_xor(x, 2);
            x += __shfl_xor(x, 4);
            x += __shfl_xor(x, 8);
            p[m][r] = x;
        }
    if (gl == 0) {
        #pragma unroll
        for (int m = 0; m < 4; ++m)
            #pragma unroll
            for (int r = 0; r < 4; ++r)
                part[w][m * 16 + rg * 4 + r] = p[m][r];
    }
    __syncthreads();

    if (t < 64) {
        float e = 0.f;
        #pragma unroll
        for (int q = 0; q < 8; ++q) e += part[q][t];
        energy[(size_t)b * SEQ + s0 + t] = e;
    }
}

// ---------------------------------------------------------------------------
// K3: softmax over s per b, IN PLACE on the attn region of d_out.
// ---------------------------------------------------------------------------
__global__ void k_softmax(float* __restrict__ attn)
{
    __shared__ float redm[4], reds[4];
    const int b = blockIdx.x, t = threadIdx.x;
    float* e = attn + (size_t)b * SEQ;

    float4 ev[4];
    float m = -3.4e38f;
    #pragma unroll
    for (int i = 0; i < 4; ++i) {
        ev[i] = *reinterpret_cast<const float4*>(e + i * 1024 + t * 4);
        m = fmaxf(m, fmaxf(fmaxf(ev[i].x, ev[i].y), fmaxf(ev[i].z, ev[i].w)));
    }
    #pragma unroll
    for (int off = 1; off < 64; off <<= 1) m = fmaxf(m, __shfl_xor(m, off));
    if ((t & 63) == 0) redm[t >> 6] = m;
    __syncthreads();
    m = fmaxf(fmaxf(redm[0], redm[1]), fmaxf(redm[2], redm[3]));

    float s = 0.f;
    #pragma unroll
    for (int i = 0; i < 4; ++i) {
        ev[i].x = __expf(ev[i].x - m);  ev[i].y = __expf(ev[i].y - m);
        ev[i].z = __expf(ev[i].z - m);  ev[i].w = __expf(ev[i].w - m);
        s += (ev[i].x + ev[i].y) + (ev[i].z + ev[i].w);
    }
    #pragma unroll
    for (int off = 1; off < 64; off <<= 1) s += __shfl_xor(s, off);
    if ((t & 63) == 0) reds[t >> 6] = s;
    __syncthreads();
    s = (reds[0] + reds[1]) + (reds[2] + reds[3]);
    const float inv = 1.0f / s;

    #pragma unroll
    for (int i = 0; i < 4; ++i) {
        const float4 w4 = make_float4(ev[i].x * inv, ev[i].y * inv,
                                      ev[i].z * inv, ev[i].w * inv);
        *reinterpret_cast<float4*>(e + i * 1024 + t * 4) = w4;
    }
}

// ---------------------------------------------------------------------------
// K4: partial context. grid = (64 b, 16 s-splits), 256 threads.
// ---------------------------------------------------------------------------
__global__ void k_ctxpart(const float* __restrict__ enc,
                          const float* __restrict__ attn,
                          float* __restrict__ pctx)
{
    __shared__ float w[256];
    const int b  = blockIdx.x;
    const int sp = blockIdx.y;
    const int t  = threadIdx.x;

    w[t] = attn[(size_t)b * SEQ + sp * 256 + t];
    __syncthreads();

    const float2* e2 = reinterpret_cast<const float2*>(enc);
    size_t idx = ((size_t)sp * 256 * BATCH + b) * (HID / 2) + t;
    const size_t stride = (size_t)BATCH * (HID / 2);

    float ax = 0.f, ay = 0.f;
    #pragma unroll 4
    for (int s = 0; s < 256; ++s) {
        const float2 ev = e2[idx];
        const float ws = w[s];
        ax = fmaf(ws, ev.x, ax);
        ay = fmaf(ws, ev.y, ay);
        idx += stride;
    }
    float2* p2 = reinterpret_cast<float2*>(pctx);
    p2[((size_t)sp * BATCH + b) * (HID / 2) + t] = make_float2(ax, ay);
}

// ---------------------------------------------------------------------------
// K5: context[b][h] = sum over 16 splits.
// ---------------------------------------------------------------------------
__global__ void k_ctxsum(const float* __restrict__ pctx,
                         float* __restrict__ ctx)
{
    const int i = blockIdx.x * 256 + threadIdx.x;
    float s = 0.f;
    #pragma unroll
    for (int sp = 0; sp < 16; ++sp) s += pctx[(size_t)sp * BATCH * HID + i];
    ctx[i] = s;
}

// ---------------------------------------------------------------------------
extern "C" void kernel_launch(void* const* d_in, const int* in_sizes, int n_in,
                              void* d_out, int out_size, void* d_ws, size_t ws_size,
                              hipStream_t stream)
{
    const float* dh  = (const float*)d_in[0];
    const float* enc = (const float*)d_in[1];
    const float* W1  = (const float*)d_in[2];
    const float* W2  = (const float*)d_in[3];
    const float* v   = (const float*)d_in[4];

    float* out  = (float*)d_out;
    float* ctx  = out;                           // 64*512
    float* attn = out + BATCH * HID;             // 64*4096 (energy -> softmax in place)

    float*  dp   = (float*)d_ws;                 // 128 KiB
    ushort* W2t  = (ushort*)(dp + BATCH * HID);  // 512 KiB (fragment order)
    float*  pctx = (float*)(W2t + HID * HID);    // 2 MiB

    k_cvtW2  <<<128, 256, 0, stream>>>(W2, W2t);
    k_decproj<<<HID, 256, 0, stream>>>(dh, W1, dp);
    k_energy <<<4096, 512, 0, stream>>>(enc, W2t, dp, v, attn);
    k_softmax<<<BATCH, 256, 0, stream>>>(attn);
    k_ctxpart<<<dim3(BATCH, 16), 256, 0, stream>>>(enc, attn, pctx);
    k_ctxsum <<<BATCH * HID / 256, 256, 0, stream>>>(pctx, ctx);
}